// Round 2
// baseline (170.347 us; speedup 1.0000x reference)
//
#include <hip/hip_runtime.h>
#include <hip/hip_bf16.h>

// Problem constants (fixed by setup_inputs in the reference)
constexpr int ALL_NODES = 12288;
constexpr int FEA       = 32;
constexpr int N_PERM    = 6144;     // 8*4*192 pooled nodes
constexpr int N_EDGES   = 393216;
constexpr int NODE_NUM  = 192;      // pooled nodes per window
constexpr int WINxNODE  = 768;      // slide_win_num * NODE_NUM

// Workspace layout (fp32 elements)
constexpr int ACC_OFF  = 0;                          // [ALL_NODES*FEA] A@y accumulator
constexpr int Y_OFF    = ACC_OFF  + ALL_NODES * FEA; // [ALL_NODES*FEA] d*x_zero
constexpr int ACCA_OFF = Y_OFF    + ALL_NODES * FEA; // [ALL_NODES] A@ya accumulator
constexpr int YA_OFF   = ACCA_OFF + ALL_NODES;       // [ALL_NODES] d*atte_zero
constexpr int DEG_OFF  = YA_OFF   + ALL_NODES;       // [ALL_NODES] row degree (init 1.0 = self loop)
constexpr int D_OFF    = DEG_OFF  + ALL_NODES;       // [ALL_NODES] rsqrt(deg)
constexpr int WS_TOTAL = D_OFF    + ALL_NODES;       // 835584 floats ~= 3.2 MB

__global__ void k_init(float* ws) {
    int i = blockIdx.x * blockDim.x + threadIdx.x;
    if (i < WS_TOTAL)
        ws[i] = (i >= DEG_OFF && i < DEG_OFF + ALL_NODES) ? 1.0f : 0.0f;
}

__global__ void k_deg(const int* __restrict__ row, const float* __restrict__ attr,
                      float* __restrict__ deg) {
    int e = blockIdx.x * blockDim.x + threadIdx.x;
    if (e < N_EDGES)
        atomicAdd(&deg[row[e]], attr[e]);
}

__global__ void k_rsqrt(const float* __restrict__ deg, float* __restrict__ d) {
    int i = blockIdx.x * blockDim.x + threadIdx.x;
    if (i < ALL_NODES)
        d[i] = rsqrtf(deg[i]);
}

// One thread per (pooled node k, feature f). perm is unique -> no conflicts.
__global__ void k_scatter(const float* __restrict__ fea,
                          const int* __restrict__ perm,
                          const float* __restrict__ nac,
                          const float* __restrict__ d,
                          float* __restrict__ y, float* __restrict__ ya) {
    int t = blockIdx.x * blockDim.x + threadIdx.x;
    if (t >= N_PERM * FEA) return;
    int k = t >> 5, f = t & 31;
    int p = perm[k];
    float dp = d[p];
    y[p * FEA + f] = dp * fea[t];
    if (f == 0) {
        int b = k / WINxNODE;          // batch index
        int n = k % NODE_NUM;          // node-within-window index
        ya[p] = dp * nac[b * NODE_NUM + n];
    }
}

// One thread per (edge e, feature f). 32 consecutive lanes share an edge:
// y-read and acc-atomic are both coalesced 128B transactions.
__global__ void k_spmv(const int* __restrict__ ei0, const int* __restrict__ ei1,
                       const float* __restrict__ attr,
                       const float* __restrict__ y, const float* __restrict__ ya,
                       float* __restrict__ acc, float* __restrict__ acca) {
    long long t = (long long)blockIdx.x * blockDim.x + threadIdx.x;
    if (t >= (long long)N_EDGES * FEA) return;
    int e = (int)(t >> 5), f = (int)(t & 31);
    int i = ei0[e];
    int j = ei1[e];
    float w = attr[e];
    atomicAdd(&acc[i * FEA + f], w * y[j * FEA + f]);
    if (f == 0)
        atomicAdd(&acca[i], w * ya[j]);
}

// out = d * (A_sparse@y + y)   (the +y is the identity self-loop)
__global__ void k_final(const float* __restrict__ acc, const float* __restrict__ acca,
                        const float* __restrict__ y, const float* __restrict__ ya,
                        const float* __restrict__ d,
                        float* __restrict__ out_x,
                        float* __restrict__ out_a) {
    int t = blockIdx.x * blockDim.x + threadIdx.x;
    if (t >= ALL_NODES * FEA) return;
    int i = t >> 5, f = t & 31;
    float di = d[i];
    out_x[t] = di * (acc[t] + y[t]);
    if (f == 0)
        out_a[i] = di * (acca[i] + ya[i]);
}

extern "C" void kernel_launch(void* const* d_in, const int* in_sizes, int n_in,
                              void* d_out, int out_size, void* d_ws, size_t ws_size,
                              hipStream_t stream) {
    const float* fea  = (const float*)d_in[0];
    const int*   perm = (const int*)d_in[1];
    const int*   ei   = (const int*)d_in[2];   // (2, N_EDGES) row-major
    const float* attr = (const float*)d_in[3];
    const float* nac  = (const float*)d_in[4];

    float* ws = (float*)d_ws;
    float* acc  = ws + ACC_OFF;
    float* y    = ws + Y_OFF;
    float* acca = ws + ACCA_OFF;
    float* ya   = ws + YA_OFF;
    float* deg  = ws + DEG_OFF;
    float* dv   = ws + D_OFF;

    float* out_x = (float*)d_out;                 // (12288, 32)
    float* out_a = out_x + ALL_NODES * FEA;       // (12288,)

    constexpr int B = 256;
    k_init   <<<(WS_TOTAL        + B - 1) / B, B, 0, stream>>>(ws);
    k_deg    <<<(N_EDGES         + B - 1) / B, B, 0, stream>>>(ei, attr, deg);
    k_rsqrt  <<<(ALL_NODES       + B - 1) / B, B, 0, stream>>>(deg, dv);
    k_scatter<<<(N_PERM * FEA    + B - 1) / B, B, 0, stream>>>(fea, perm, nac, dv, y, ya);
    k_spmv   <<<(N_EDGES * FEA   + B - 1) / B, B, 0, stream>>>(ei, ei + N_EDGES, attr, y, ya, acc, acca);
    k_final  <<<(ALL_NODES * FEA + B - 1) / B, B, 0, stream>>>(acc, acca, y, ya, dv, out_x, out_a);
}